// Round 8
// baseline (196.230 us; speedup 1.0000x reference)
//
#include <hip/hip_runtime.h>
#include <stdint.h>

#define BB 2
#define HH 16
#define LL 2048
#define DD 1024

typedef __bf16 b16x8 __attribute__((ext_vector_type(8)));
typedef __bf16 b16x4 __attribute__((ext_vector_type(4)));
typedef float f32x4 __attribute__((ext_vector_type(4)));

__device__ __forceinline__ short f2bf(float f) {
  unsigned u = __builtin_bit_cast(unsigned, f);
  return (short)((u + 0x7fffu + ((u >> 16) & 1u)) >> 16);
}

// native bf16 convert
__device__ __forceinline__ short bfc(float f) {
  return __builtin_bit_cast(short, static_cast<__bf16>(f));
}

__device__ __forceinline__ void gl_lds16(const void* gp, void* lp) {
  __builtin_amdgcn_global_load_lds(
      (const __attribute__((address_space(1))) void*)gp,
      (__attribute__((address_space(3))) void*)lp, 16, 0, 0);
}

// ---------------- X f32 -> bf16 ----------------
__global__ __launch_bounds__(256) void xcvt(const float* __restrict__ X,
                                            short* __restrict__ Xb) {
  int i = blockIdx.x * 256 + threadIdx.x;
  float4 v = ((const float4*)X)[i];
  short4 o;
  o.x = f2bf(v.x); o.y = f2bf(v.y); o.z = f2bf(v.z); o.w = f2bf(v.w);
  ((short4*)Xb)[i] = o;
}

// ---------------- W[k][n] f32 -> Wt[n][k] bf16 (4 mats via blockIdx.z) ------
__global__ __launch_bounds__(256) void wtrans(const float* __restrict__ W0,
                                              const float* __restrict__ W1,
                                              const float* __restrict__ W2,
                                              const float* __restrict__ W3,
                                              short* __restrict__ Wt) {
  __shared__ float t[32][33];
  const float* W = blockIdx.z == 0 ? W0 : blockIdx.z == 1 ? W1
                 : blockIdx.z == 2 ? W2 : W3;
  short* dst = Wt + (size_t)blockIdx.z * DD * DD;
  int tx = threadIdx.x & 31, ty0 = threadIdx.x >> 5;
  int nb = blockIdx.x * 32, kb = blockIdx.y * 32;
#pragma unroll
  for (int i = 0; i < 4; ++i)
    t[ty0 + i * 8][tx] = W[(size_t)(kb + ty0 + i * 8) * DD + nb + tx];
  __syncthreads();
#pragma unroll
  for (int i = 0; i < 4; ++i)
    dst[(size_t)(nb + ty0 + i * 8) * DD + kb + tx] = f2bf(t[tx][ty0 + i * 8]);
}

// ---------------- fused QKV GEMM: [4096,1024] @ Wt -> Q,K,Vt ---------------
__global__ __launch_bounds__(256) void qkv_gemm(const short* __restrict__ Xb,
                                                const short* __restrict__ Wall,
                                                const float* __restrict__ bQ,
                                                const float* __restrict__ bK,
                                                const float* __restrict__ bV,
                                                short* __restrict__ Qo,
                                                short* __restrict__ Ko,
                                                short* __restrict__ Vto) {
  __shared__ __align__(16) short As[128 * 32];
  __shared__ __align__(16) short Bs[128 * 32];

  const int tid = threadIdx.x;
  const int lane = tid & 63;
  const int wid = tid >> 6;
  const int m0 = blockIdx.y * 128;
  const int ng = blockIdx.x * 128;
  const int sel = ng >> 10;
  const int n0 = ng & 1023;
  const short* W = Wall + (size_t)sel * DD * DD;

  const int wrow = wid >> 1, wcol = wid & 1;
  const int lrow = lane & 15;
  const int lk8 = (lane >> 4) * 8;
  const int srow = lane >> 2;
  const int scol = (lane & 3) * 8;

  f32x4 z4 = {0.f, 0.f, 0.f, 0.f};
  f32x4 acc[4][4];
#pragma unroll
  for (int i = 0; i < 4; ++i)
#pragma unroll
    for (int j = 0; j < 4; ++j) acc[i][j] = z4;

  for (int kt = 0; kt < DD; kt += 32) {
#pragma unroll
    for (int i = 0; i < 2; ++i) {
      int c = wid * 2 + i;
      gl_lds16(Xb + (size_t)(m0 + c * 16 + srow) * DD + kt + scol, As + c * 512);
      gl_lds16(W + (size_t)(n0 + c * 16 + srow) * DD + kt + scol, Bs + c * 512);
    }
    __syncthreads();
    b16x8 a[4], b[4];
#pragma unroll
    for (int i = 0; i < 4; ++i)
      a[i] = *(const b16x8*)(As + (wrow * 64 + i * 16 + lrow) * 32 + lk8);
#pragma unroll
    for (int j = 0; j < 4; ++j)
      b[j] = *(const b16x8*)(Bs + (wcol * 64 + j * 16 + lrow) * 32 + lk8);
#pragma unroll
    for (int i = 0; i < 4; ++i)
#pragma unroll
      for (int j = 0; j < 4; ++j)
        acc[i][j] = __builtin_amdgcn_mfma_f32_16x16x32_bf16(a[i], b[j], acc[i][j], 0, 0, 0);
    __syncthreads();
  }

  const float* bias = sel == 0 ? bQ : sel == 1 ? bK : bV;
  float bv[4];
#pragma unroll
  for (int j = 0; j < 4; ++j) bv[j] = bias[n0 + wcol * 64 + j * 16 + lrow];

  const int rbase = (lane >> 4) * 4;
  if (sel == 2) {
    // V: write transposed (B,H,DK,L) so attention PV reads are contiguous.
#pragma unroll
    for (int i = 0; i < 4; ++i) {
      int gm = m0 + wrow * 64 + i * 16 + rbase;
      int bb = gm >> 11, lb = gm & 2047;
#pragma unroll
      for (int j = 0; j < 4; ++j) {
        int gn = n0 + wcol * 64 + j * 16 + lrow;
        int h = gn >> 6, dk = gn & 63;
        short4 pk;
        pk.x = bfc(acc[i][j][0] + bv[j]);
        pk.y = bfc(acc[i][j][1] + bv[j]);
        pk.z = bfc(acc[i][j][2] + bv[j]);
        pk.w = bfc(acc[i][j][3] + bv[j]);
        *(short4*)(Vto + ((size_t)((bb * HH + h) * 64 + dk)) * LL + lb) = pk;
      }
    }
  } else {
    short* dst = sel == 0 ? Qo : Ko;
    // Q: fold 1/sqrt(64) AND log2(e) so softmax runs in exp2 domain.
    float sc = sel == 0 ? 0.18033688011112042f : 1.0f;
#pragma unroll
    for (int i = 0; i < 4; ++i) {
      int gm = m0 + wrow * 64 + i * 16 + rbase;
#pragma unroll
      for (int j = 0; j < 4; ++j) {
        int gn = n0 + wcol * 64 + j * 16 + lrow;
        int h = gn >> 6, dk = gn & 63;
#pragma unroll
        for (int r = 0; r < 4; ++r) {
          int m = gm + r;
          int bb = m >> 11, lq = m & 2047;
          dst[((size_t)(bb * HH + h) * LL + lq) * 64 + dk] =
              bfc((acc[i][j][r] + bv[j]) * sc);
        }
      }
    }
  }
}

// ---------------- flash attention (swapped-operand P, V direct-to-reg) ----
// grid (16, 32): 128 q-rows/block, 4 waves x 32 rows. K LDS-staged (b128
// reads, conflict-free swizzle, gl_lds dbuf). V bypasses LDS: coalesced 8B
// global->VGPR loads, register-double-buffered one tile ahead (latency
// hidden under softmax+PV+QK). S^T = mfma(K,Q) keeps P in-register for PV
// (key-permutation-invariant tau ordering). Counted vmcnt(16) at barriers
// retires only the 2 K gl_lds, leaving 16 V loads in flight (T4).
__global__ __launch_bounds__(256, 2) void attn(const short* __restrict__ Qg,
                                               const short* __restrict__ Kg,
                                               const short* __restrict__ Vt,
                                               short* __restrict__ Og) {
  __shared__ __align__(16) short Ks[2][64 * 64];  // [key][d], swizzled rows

  const int tid = threadIdx.x;
  const int lane = tid & 63;
  const int wid = tid >> 6;
  const int bh = blockIdx.y;
  const int q0 = blockIdx.x * 128 + wid * 32;

  const short* Qb = Qg + (size_t)bh * LL * 64;
  const short* Kb = Kg + (size_t)bh * LL * 64;
  const short* Vb = Vt + (size_t)bh * 64 * LL;

  const int lrow = lane & 15;
  const int hi = lane >> 4;     // 0..3
  const int hi8 = hi * 8;       // shorts
  const int hi16b = hi * 16;    // bytes
  const int r8 = lane >> 3;     // staging row within 8-row chunk
  const int c8 = lane & 7;
  const int swz8 = (c8 ^ r8) * 8;  // pre-swizzled global source offset (elems)

  // Q fragment: B-operand of swapped QK (col=q=lrow, k=hi*8+j)
  b16x8 qf[2][2];
#pragma unroll
  for (int f = 0; f < 2; ++f)
#pragma unroll
    for (int ks = 0; ks < 2; ++ks)
      qf[f][ks] = *(const b16x8*)(Qb + (size_t)(q0 + f * 16 + lrow) * 64 + ks * 32 + hi8);

  f32x4 z4 = {0.f, 0.f, 0.f, 0.f};
  f32x4 accO[2][4];            // accO[f][db]: O^T[d=db*16+hi*4+r][q=f*16+lrow]
  float m_i[2], l_i[2];        // per-q scalars; l_i LANE-PARTIAL across hi
#pragma unroll
  for (int f = 0; f < 2; ++f) {
#pragma unroll
    for (int d = 0; d < 4; ++d) accO[f][d] = z4;
    m_i[f] = -1e30f; l_i[f] = 0.f;
  }

  b16x8 vA[4][2], vB[4][2];

  // V fragment (A-operand): V[row=db*16+lrow][key=(2ks+(j>>2))*16+hi*4+(j&3)]
  // per instr: 16 rows x 32 contiguous bytes -> coalesced, L1/L2-served.
#define LOAD_V(DST, KT)                                                         \
  {                                                                             \
    _Pragma("unroll") for (int db = 0; db < 4; ++db) {                          \
      const short* vb = Vb + (size_t)(db * 16 + lrow) * LL + (KT) * 64 + hi * 4;\
      _Pragma("unroll") for (int ks = 0; ks < 2; ++ks) {                        \
        b16x4 vlo = *(const b16x4*)(vb + (2 * ks) * 16);                        \
        b16x4 vhi = *(const b16x4*)(vb + (2 * ks + 1) * 16);                    \
        DST[db][ks] = __builtin_shufflevector(vlo, vhi, 0, 1, 2, 3, 4, 5, 6, 7);\
      }                                                                         \
    }                                                                           \
  }

  // prologue: stage K tile 0 (first -> oldest in vmcnt), then V tile 0
#pragma unroll
  for (int i = 0; i < 2; ++i) {
    int c = wid * 2 + i;
    gl_lds16(Kb + (size_t)(c * 8 + r8) * 64 + swz8, &Ks[0][c * 512]);
  }
  LOAD_V(vA, 0);
  asm volatile("s_waitcnt vmcnt(16)" ::: "memory");  // K gl_lds (2 oldest) done
  __syncthreads();

#define TILE(VC, VN, KT, CUR)                                                   \
  {                                                                             \
    /* prefetch next K tile into the other LDS buffer (issued FIRST) */         \
    if ((KT) + 1 < 32) {                                                        \
      _Pragma("unroll") for (int i = 0; i < 2; ++i) {                           \
        int c = wid * 2 + i;                                                    \
        gl_lds16(Kb + (size_t)(((KT) + 1) * 64 + c * 8 + r8) * 64 + swz8,       \
                 &Ks[(CUR) ^ 1][c * 512]);                                      \
      }                                                                         \
    }                                                                           \
    /* S^T = mfma(K, Q): sacc[f][kf][r] = S[key=kf*16+hi*4+r][q=f*16+lrow] */   \
    f32x4 sacc[2][4];                                                           \
    _Pragma("unroll") for (int f = 0; f < 2; ++f)                               \
        _Pragma("unroll") for (int kf = 0; kf < 4; ++kf) sacc[f][kf] = z4;      \
    __builtin_amdgcn_s_setprio(1);                                              \
    _Pragma("unroll") for (int kf = 0; kf < 4; ++kf) {                          \
      int key = kf * 16 + lrow;                                                 \
      int sw = (key & 7) << 4;                                                  \
      _Pragma("unroll") for (int ks = 0; ks < 2; ++ks) {                        \
        b16x8 kfr = *(const b16x8*)(&Ks[CUR][0] + key * 64 +                    \
                                    (((ks * 64 + hi16b) ^ sw) >> 1));           \
        _Pragma("unroll") for (int f = 0; f < 2; ++f)                           \
            sacc[f][kf] = __builtin_amdgcn_mfma_f32_16x16x32_bf16(              \
                kfr, qf[f][ks], sacc[f][kf], 0, 0, 0);                          \
      }                                                                         \
    }                                                                           \
    __builtin_amdgcn_s_setprio(0);                                              \
    /* issue V loads for the NEXT tile (land during next tile's QK) */          \
    LOAD_V(VN, ((KT) + 1) & 31);                                                \
    /* defer-max online softmax (keys lane-local) */                            \
    float lm[2];                                                                \
    _Pragma("unroll") for (int f = 0; f < 2; ++f) {                             \
      float mx = sacc[f][0][0];                                                 \
      _Pragma("unroll") for (int kf = 0; kf < 4; ++kf)                          \
          _Pragma("unroll") for (int r = 0; r < 4; ++r)                         \
              mx = fmaxf(mx, sacc[f][kf][r]);                                   \
      lm[f] = mx;                                                               \
    }                                                                           \
    float w = fmaxf(lm[0] - m_i[0], lm[1] - m_i[1]);                            \
    if (!__all(w <= 8.0f)) {                                                    \
      _Pragma("unroll") for (int f = 0; f < 2; ++f) {                           \
        float mx = lm[f];                                                       \
        mx = fmaxf(mx, __shfl_xor(mx, 16));                                     \
        mx = fmaxf(mx, __shfl_xor(mx, 32));                                     \
        float mnew = fmaxf(m_i[f], mx);                                         \
        float corr = __builtin_amdgcn_exp2f(m_i[f] - mnew);                     \
        l_i[f] *= corr;                                                         \
        m_i[f] = mnew;                                                          \
        _Pragma("unroll") for (int d = 0; d < 4; ++d) accO[f][d] *= corr;       \
      }                                                                         \
    }                                                                           \
    /* P = exp2(S - m) packed straight into the PV B-fragment */                \
    b16x8 pfr[2][2];                                                            \
    _Pragma("unroll") for (int f = 0; f < 2; ++f) {                             \
      float ps = 0.f;                                                           \
      _Pragma("unroll") for (int kf = 0; kf < 4; ++kf)                          \
          _Pragma("unroll") for (int r = 0; r < 4; ++r) {                       \
        float p = __builtin_amdgcn_exp2f(sacc[f][kf][r] - m_i[f]);              \
        ps += p;                                                                \
        pfr[f][kf >> 1][(kf & 1) * 4 + r] = static_cast<__bf16>(p);             \
      }                                                                         \
      l_i[f] += ps;                                                             \
    }                                                                           \
    /* O^T += mfma(V, P) */                                                     \
    __builtin_amdgcn_s_setprio(1);                                              \
    _Pragma("unroll") for (int f = 0; f < 2; ++f)                               \
        _Pragma("unroll") for (int db = 0; db < 4; ++db)                        \
            _Pragma("unroll") for (int ks = 0; ks < 2; ++ks)                    \
                accO[f][db] = __builtin_amdgcn_mfma_f32_16x16x32_bf16(          \
                    VC[db][ks], pfr[f][ks], accO[f][db], 0, 0, 0);              \
    __builtin_amdgcn_s_setprio(0);                                              \
    /* retire the 2 K gl_lds (oldest); leave 16 V loads in flight */            \
    asm volatile("s_waitcnt vmcnt(16)" ::: "memory");                           \
    __syncthreads();                                                            \
  }

  for (int kt = 0; kt < 32; kt += 2) {
    TILE(vA, vB, kt, 0);
    TILE(vB, vA, kt + 1, 1);
  }
#undef TILE
#undef LOAD_V

  // epilogue: reduce lane-partial l across hi, O /= l, packed short4 stores
  const int bb = bh >> 4, h = bh & 15;
#pragma unroll
  for (int f = 0; f < 2; ++f) {
    float l = l_i[f];
    l += __shfl_xor(l, 16);
    l += __shfl_xor(l, 32);
    float rl = 1.0f / l;
    int q = q0 + f * 16 + lrow;
#pragma unroll
    for (int db = 0; db < 4; ++db) {
      short4 pk;
      pk.x = bfc(accO[f][db][0] * rl);
      pk.y = bfc(accO[f][db][1] * rl);
      pk.z = bfc(accO[f][db][2] * rl);
      pk.w = bfc(accO[f][db][3] * rl);
      *(short4*)(Og + (size_t)(bb * LL + q) * DD + h * 64 + db * 16 + hi * 4) = pk;
    }
  }
}

// ---------------- output GEMM: attn[4096,1024] @ WOt + bO -> f32 ----------
__global__ __launch_bounds__(256) void out_gemm(const short* __restrict__ Ab,
                                                const short* __restrict__ Wt,
                                                const float* __restrict__ bO,
                                                float* __restrict__ Out) {
  __shared__ __align__(16) short As[128 * 32];
  __shared__ __align__(16) short Bs[128 * 32];

  const int tid = threadIdx.x;
  const int lane = tid & 63;
  const int wid = tid >> 6;
  const int m0 = blockIdx.y * 128;
  const int n0 = blockIdx.x * 128;

  const int wrow = wid >> 1, wcol = wid & 1;
  const int lrow = lane & 15;
  const int lk8 = (lane >> 4) * 8;
  const int srow = lane >> 2;
  const int scol = (lane & 3) * 8;

  f32x4 z4 = {0.f, 0.f, 0.f, 0.f};
  f32x4 acc[4][4];
#pragma unroll
  for (int i = 0; i < 4; ++i)
#pragma unroll
    for (int j = 0; j < 4; ++j) acc[i][j] = z4;

  for (int kt = 0; kt < DD; kt += 32) {
#pragma unroll
    for (int i = 0; i < 2; ++i) {
      int c = wid * 2 + i;
      gl_lds16(Ab + (size_t)(m0 + c * 16 + srow) * DD + kt + scol, As + c * 512);
      gl_lds16(Wt + (size_t)(n0 + c * 16 + srow) * DD + kt + scol, Bs + c * 512);
    }
    __syncthreads();
    b16x8 a[4], b[4];
#pragma unroll
    for (int i = 0; i < 4; ++i)
      a[i] = *(const b16x8*)(As + (wrow * 64 + i * 16 + lrow) * 32 + lk8);
#pragma unroll
    for (int j = 0; j < 4; ++j)
      b[j] = *(const b16x8*)(Bs + (wcol * 64 + j * 16 + lrow) * 32 + lk8);
#pragma unroll
    for (int i = 0; i < 4; ++i)
#pragma unroll
      for (int j = 0; j < 4; ++j)
        acc[i][j] = __builtin_amdgcn_mfma_f32_16x16x32_bf16(a[i], b[j], acc[i][j], 0, 0, 0);
    __syncthreads();
  }

  float bv[4];
#pragma unroll
  for (int j = 0; j < 4; ++j) bv[j] = bO[n0 + wcol * 64 + j * 16 + lrow];

  const int rbase = (lane >> 4) * 4;
#pragma unroll
  for (int i = 0; i < 4; ++i) {
    int gm = m0 + wrow * 64 + i * 16 + rbase;
#pragma unroll
    for (int j = 0; j < 4; ++j) {
      int gn = n0 + wcol * 64 + j * 16 + lrow;
#pragma unroll
      for (int r = 0; r < 4; ++r)
        Out[(size_t)(gm + r) * DD + gn] = acc[i][j][r] + bv[j];
    }
  }
}

extern "C" void kernel_launch(void* const* d_in, const int* in_sizes, int n_in,
                              void* d_out, int out_size, void* d_ws, size_t ws_size,
                              hipStream_t stream) {
  const float* X = (const float*)d_in[0];
  const float* WQ = (const float*)d_in[1];
  const float* bQ = (const float*)d_in[2];
  const float* WK = (const float*)d_in[3];
  const float* bK = (const float*)d_in[4];
  const float* WV = (const float*)d_in[5];
  const float* bV = (const float*)d_in[6];
  const float* WO = (const float*)d_in[7];
  const float* bO = (const float*)d_in[8];
  float* Out = (float*)d_out;

  // workspace layout (shorts): Xb 4M | Wt 4x1M | Q 4M | K 4M | Vt 4M | At 4M
  if (ws_size < (size_t)24 * 1024 * 1024 * 2) return;
  short* ws = (short*)d_ws;
  short* Xb = ws;
  short* Wt = Xb + (size_t)4096 * 1024;
  short* Qb = Wt + (size_t)4 * 1024 * 1024;
  short* Kb = Qb + (size_t)4096 * 1024;
  short* Vtb = Kb + (size_t)4096 * 1024;
  short* At = Vtb + (size_t)4096 * 1024;

  hipLaunchKernelGGL(xcvt, dim3(4096), dim3(256), 0, stream, X, Xb);
  hipLaunchKernelGGL(wtrans, dim3(32, 32, 4), dim3(256), 0, stream, WQ, WK, WV, WO, Wt);
  hipLaunchKernelGGL(qkv_gemm, dim3(24, 32), dim3(256), 0, stream, Xb, Wt, bQ, bK, bV,
                     Qb, Kb, Vtb);
  hipLaunchKernelGGL(attn, dim3(16, 32), dim3(256), 0, stream, Qb, Kb, Vtb, At);
  hipLaunchKernelGGL(out_gemm, dim3(8, 32), dim3(256), 0, stream, At,
                     Wt + (size_t)3 * 1024 * 1024, bO, Out);
}

// Round 9
// 117.902 us; speedup vs baseline: 1.6643x; 1.6643x over previous
//
#include <hip/hip_runtime.h>
#include <stdint.h>

#define BB 2
#define HH 16
#define LL 2048
#define DD 1024

typedef __bf16 b16x8 __attribute__((ext_vector_type(8)));
typedef __bf16 b16x4 __attribute__((ext_vector_type(4)));
typedef float f32x4 __attribute__((ext_vector_type(4)));

__device__ __forceinline__ short f2bf(float f) {
  unsigned u = __builtin_bit_cast(unsigned, f);
  return (short)((u + 0x7fffu + ((u >> 16) & 1u)) >> 16);
}

// native bf16 convert
__device__ __forceinline__ short bfc(float f) {
  return __builtin_bit_cast(short, static_cast<__bf16>(f));
}

__device__ __forceinline__ void gl_lds16(const void* gp, void* lp) {
  __builtin_amdgcn_global_load_lds(
      (const __attribute__((address_space(1))) void*)gp,
      (__attribute__((address_space(3))) void*)lp, 16, 0, 0);
}

// ---------------- X f32 -> bf16 ----------------
__global__ __launch_bounds__(256) void xcvt(const float* __restrict__ X,
                                            short* __restrict__ Xb) {
  int i = blockIdx.x * 256 + threadIdx.x;
  float4 v = ((const float4*)X)[i];
  short4 o;
  o.x = f2bf(v.x); o.y = f2bf(v.y); o.z = f2bf(v.z); o.w = f2bf(v.w);
  ((short4*)Xb)[i] = o;
}

// ---------------- W[k][n] f32 -> Wt[n][k] bf16 (4 mats via blockIdx.z) ------
__global__ __launch_bounds__(256) void wtrans(const float* __restrict__ W0,
                                              const float* __restrict__ W1,
                                              const float* __restrict__ W2,
                                              const float* __restrict__ W3,
                                              short* __restrict__ Wt) {
  __shared__ float t[32][33];
  const float* W = blockIdx.z == 0 ? W0 : blockIdx.z == 1 ? W1
                 : blockIdx.z == 2 ? W2 : W3;
  short* dst = Wt + (size_t)blockIdx.z * DD * DD;
  int tx = threadIdx.x & 31, ty0 = threadIdx.x >> 5;
  int nb = blockIdx.x * 32, kb = blockIdx.y * 32;
#pragma unroll
  for (int i = 0; i < 4; ++i)
    t[ty0 + i * 8][tx] = W[(size_t)(kb + ty0 + i * 8) * DD + nb + tx];
  __syncthreads();
#pragma unroll
  for (int i = 0; i < 4; ++i)
    dst[(size_t)(nb + ty0 + i * 8) * DD + kb + tx] = f2bf(t[tx][ty0 + i * 8]);
}

// ---------------- fused QKV GEMM: [4096,1024] @ Wt -> Q,K,Vt ---------------
__global__ __launch_bounds__(256) void qkv_gemm(const short* __restrict__ Xb,
                                                const short* __restrict__ Wall,
                                                const float* __restrict__ bQ,
                                                const float* __restrict__ bK,
                                                const float* __restrict__ bV,
                                                short* __restrict__ Qo,
                                                short* __restrict__ Ko,
                                                short* __restrict__ Vto) {
  __shared__ __align__(16) short As[128 * 32];
  __shared__ __align__(16) short Bs[128 * 32];

  const int tid = threadIdx.x;
  const int lane = tid & 63;
  const int wid = tid >> 6;
  const int m0 = blockIdx.y * 128;
  const int ng = blockIdx.x * 128;
  const int sel = ng >> 10;
  const int n0 = ng & 1023;
  const short* W = Wall + (size_t)sel * DD * DD;

  const int wrow = wid >> 1, wcol = wid & 1;
  const int lrow = lane & 15;
  const int lk8 = (lane >> 4) * 8;
  const int srow = lane >> 2;
  const int scol = (lane & 3) * 8;

  f32x4 z4 = {0.f, 0.f, 0.f, 0.f};
  f32x4 acc[4][4];
#pragma unroll
  for (int i = 0; i < 4; ++i)
#pragma unroll
    for (int j = 0; j < 4; ++j) acc[i][j] = z4;

  for (int kt = 0; kt < DD; kt += 32) {
#pragma unroll
    for (int i = 0; i < 2; ++i) {
      int c = wid * 2 + i;
      gl_lds16(Xb + (size_t)(m0 + c * 16 + srow) * DD + kt + scol, As + c * 512);
      gl_lds16(W + (size_t)(n0 + c * 16 + srow) * DD + kt + scol, Bs + c * 512);
    }
    __syncthreads();
    b16x8 a[4], b[4];
#pragma unroll
    for (int i = 0; i < 4; ++i)
      a[i] = *(const b16x8*)(As + (wrow * 64 + i * 16 + lrow) * 32 + lk8);
#pragma unroll
    for (int j = 0; j < 4; ++j)
      b[j] = *(const b16x8*)(Bs + (wcol * 64 + j * 16 + lrow) * 32 + lk8);
#pragma unroll
    for (int i = 0; i < 4; ++i)
#pragma unroll
      for (int j = 0; j < 4; ++j)
        acc[i][j] = __builtin_amdgcn_mfma_f32_16x16x32_bf16(a[i], b[j], acc[i][j], 0, 0, 0);
    __syncthreads();
  }

  const float* bias = sel == 0 ? bQ : sel == 1 ? bK : bV;
  float bv[4];
#pragma unroll
  for (int j = 0; j < 4; ++j) bv[j] = bias[n0 + wcol * 64 + j * 16 + lrow];

  const int rbase = (lane >> 4) * 4;
  if (sel == 2) {
    // V: write transposed (B,H,DK,L) with keys PERMUTED within each 64-tile:
    // addr(key)= (kf>>1)*32 + hi*8 + (kf&1)*4 + t  (kf=key>>4, hi=(key>>2)&3,
    // t=key&3), so the attention PV fragment = one contiguous 16B b128 read.
#pragma unroll
    for (int i = 0; i < 4; ++i) {
      int gm = m0 + wrow * 64 + i * 16 + rbase;
      int bb = gm >> 11, lb = gm & 2047;
      int x = lb & 63;
      int kf = x >> 4;
      int lbp = (lb & ~63) | ((kf >> 1) << 5) | (((x >> 2) & 3) << 3) | ((kf & 1) << 2);
#pragma unroll
      for (int j = 0; j < 4; ++j) {
        int gn = n0 + wcol * 64 + j * 16 + lrow;
        int h = gn >> 6, dk = gn & 63;
        short4 pk;
        pk.x = bfc(acc[i][j][0] + bv[j]);
        pk.y = bfc(acc[i][j][1] + bv[j]);
        pk.z = bfc(acc[i][j][2] + bv[j]);
        pk.w = bfc(acc[i][j][3] + bv[j]);
        *(short4*)(Vto + ((size_t)((bb * HH + h) * 64 + dk)) * LL + lbp) = pk;
      }
    }
  } else {
    short* dst = sel == 0 ? Qo : Ko;
    // Q: fold 1/sqrt(64) AND log2(e) so softmax runs in exp2 domain.
    float sc = sel == 0 ? 0.18033688011112042f : 1.0f;
#pragma unroll
    for (int i = 0; i < 4; ++i) {
      int gm = m0 + wrow * 64 + i * 16 + rbase;
#pragma unroll
      for (int j = 0; j < 4; ++j) {
        int gn = n0 + wcol * 64 + j * 16 + lrow;
        int h = gn >> 6, dk = gn & 63;
#pragma unroll
        for (int r = 0; r < 4; ++r) {
          int m = gm + r;
          int bb = m >> 11, lq = m & 2047;
          dst[((size_t)(bb * HH + h) * LL + lq) * 64 + dk] =
              bfc((acc[i][j][r] + bv[j]) * sc);
        }
      }
    }
  }
}

// ---------------- flash attention (swapped-operand, in-register P) --------
// grid (16, 32): 128 q-rows/block, 4 waves x 32 rows. K AND V LDS-staged
// (gl_lds dbuf, XOR swizzle). V's key order is pre-permuted in memory so the
// PV fragment read is a single conflict-free ds_read_b128 — byte-identical
// access pattern to the K read. S^T = mfma(K,Q) keeps P in-register for PV;
// PV = mfma(V, P) -> O^T, packed short4 stores.
__global__ __launch_bounds__(256, 2) void attn(const short* __restrict__ Qg,
                                               const short* __restrict__ Kg,
                                               const short* __restrict__ Vt,
                                               short* __restrict__ Og) {
  __shared__ __align__(16) short Ks[2][64 * 64];  // [key][d], swizzled rows
  __shared__ __align__(16) short Vs[2][64 * 64];  // [d][perm-key], swizzled rows

  const int tid = threadIdx.x;
  const int lane = tid & 63;
  const int wid = tid >> 6;
  const int bh = blockIdx.y;
  const int q0 = blockIdx.x * 128 + wid * 32;

  const short* Qb = Qg + (size_t)bh * LL * 64;
  const short* Kb = Kg + (size_t)bh * LL * 64;
  const short* Vb = Vt + (size_t)bh * 64 * LL;

  const int lrow = lane & 15;
  const int hi = lane >> 4;     // 0..3
  const int hi8 = hi * 8;       // shorts
  const int hi16b = hi * 16;    // bytes
  const int r8 = lane >> 3;     // staging row within 8-row chunk
  const int c8 = lane & 7;
  const int swz8 = (c8 ^ r8) * 8;  // pre-swizzled global source offset (elems)

  // Q fragment: B-operand of swapped QK (col=q=lrow, k=hi*8+j)
  b16x8 qf[2][2];
#pragma unroll
  for (int f = 0; f < 2; ++f)
#pragma unroll
    for (int ks = 0; ks < 2; ++ks)
      qf[f][ks] = *(const b16x8*)(Qb + (size_t)(q0 + f * 16 + lrow) * 64 + ks * 32 + hi8);

  f32x4 z4 = {0.f, 0.f, 0.f, 0.f};
  f32x4 accO[2][4];            // accO[f][db]: O^T[d=db*16+hi*4+r][q=f*16+lrow]
  float m_i[2], l_i[2];        // per-q scalars; l_i LANE-PARTIAL across hi
#pragma unroll
  for (int f = 0; f < 2; ++f) {
#pragma unroll
    for (int d = 0; d < 4; ++d) accO[f][d] = z4;
    m_i[f] = -1e30f; l_i[f] = 0.f;
  }

  // prologue: stage tile 0 into buffer 0
#pragma unroll
  for (int i = 0; i < 2; ++i) {
    int c = wid * 2 + i;
    gl_lds16(Kb + (size_t)(c * 8 + r8) * 64 + swz8, &Ks[0][c * 512]);
    gl_lds16(Vb + (size_t)(c * 8 + r8) * LL + swz8, &Vs[0][c * 512]);
  }
  asm volatile("s_waitcnt vmcnt(0)" ::: "memory");
  __syncthreads();

  int cur = 0;
  for (int kt = 0; kt < LL / 64; ++kt) {
    // prefetch next K/V tile into the other buffer
    if (kt + 1 < LL / 64) {
#pragma unroll
      for (int i = 0; i < 2; ++i) {
        int c = wid * 2 + i;
        gl_lds16(Kb + (size_t)((kt + 1) * 64 + c * 8 + r8) * 64 + swz8,
                 &Ks[cur ^ 1][c * 512]);
        gl_lds16(Vb + (size_t)(c * 8 + r8) * LL + (kt + 1) * 64 + swz8,
                 &Vs[cur ^ 1][c * 512]);
      }
    }

    // S^T = mfma(K, Q): sacc[f][kf][r] = S[key=kf*16+hi*4+r][q=f*16+lrow]
    f32x4 sacc[2][4];
#pragma unroll
    for (int f = 0; f < 2; ++f)
#pragma unroll
      for (int kf = 0; kf < 4; ++kf) sacc[f][kf] = z4;

    __builtin_amdgcn_s_setprio(1);
#pragma unroll
    for (int kf = 0; kf < 4; ++kf) {
      int key = kf * 16 + lrow;
      int sw = (key & 7) << 4;
#pragma unroll
      for (int ks = 0; ks < 2; ++ks) {
        b16x8 kfr = *(const b16x8*)(&Ks[cur][0] + key * 64 + (((ks * 64 + hi16b) ^ sw) >> 1));
#pragma unroll
        for (int f = 0; f < 2; ++f)
          sacc[f][kf] =
              __builtin_amdgcn_mfma_f32_16x16x32_bf16(kfr, qf[f][ks], sacc[f][kf], 0, 0, 0);
      }
    }
    __builtin_amdgcn_s_setprio(0);

    // ---- defer-max online softmax (keys lane-local) ----
    float lm[2];
#pragma unroll
    for (int f = 0; f < 2; ++f) {
      float mx = sacc[f][0][0];
#pragma unroll
      for (int kf = 0; kf < 4; ++kf)
#pragma unroll
        for (int r = 0; r < 4; ++r) mx = fmaxf(mx, sacc[f][kf][r]);
      lm[f] = mx;
    }
    float w = fmaxf(lm[0] - m_i[0], lm[1] - m_i[1]);

    if (!__all(w <= 8.0f)) {
      // rare path: reduce max across the 4 hi-lanes sharing each q, rescale
#pragma unroll
      for (int f = 0; f < 2; ++f) {
        float mx = lm[f];
        mx = fmaxf(mx, __shfl_xor(mx, 16));
        mx = fmaxf(mx, __shfl_xor(mx, 32));
        float mnew = fmaxf(m_i[f], mx);
        float corr = __builtin_amdgcn_exp2f(m_i[f] - mnew);
        l_i[f] *= corr;
        m_i[f] = mnew;
#pragma unroll
        for (int d = 0; d < 4; ++d) accO[f][d] *= corr;
      }
    }

    // P = exp2(S - m) packed straight into the PV B-fragment (own regs).
    // PV k-order: tau(ks, hi*8+j) = (2ks + (j>>2))*16 + hi*4 + (j&3)
    b16x8 pfr[2][2];
#pragma unroll
    for (int f = 0; f < 2; ++f) {
      float ps = 0.f;
#pragma unroll
      for (int kf = 0; kf < 4; ++kf)
#pragma unroll
        for (int r = 0; r < 4; ++r) {
          float p = __builtin_amdgcn_exp2f(sacc[f][kf][r] - m_i[f]);
          ps += p;
          pfr[f][kf >> 1][(kf & 1) * 4 + r] = static_cast<__bf16>(p);
        }
      l_i[f] += ps;
    }

    // V fragment (A-operand): permuted key layout makes this one b128,
    // identical (conflict-free) pattern to the K read.
    b16x8 vfr[4][2];
#pragma unroll
    for (int db = 0; db < 4; ++db) {
      int row = db * 16 + lrow;
      int sw = (row & 7) << 4;
#pragma unroll
      for (int ks = 0; ks < 2; ++ks)
        vfr[db][ks] = *(const b16x8*)(&Vs[cur][0] + row * 64 +
                                      (((ks * 64 + hi16b) ^ sw) >> 1));
    }

    // O^T += mfma(V, P)
    __builtin_amdgcn_s_setprio(1);
#pragma unroll
    for (int f = 0; f < 2; ++f)
#pragma unroll
      for (int db = 0; db < 4; ++db)
#pragma unroll
        for (int ks = 0; ks < 2; ++ks)
          accO[f][db] =
              __builtin_amdgcn_mfma_f32_16x16x32_bf16(vfr[db][ks], pfr[f][ks], accO[f][db], 0, 0, 0);
    __builtin_amdgcn_s_setprio(0);

    // next tile's prefetch must have landed before flip
    asm volatile("s_waitcnt vmcnt(0)" ::: "memory");
    __syncthreads();
    cur ^= 1;
  }

  // epilogue: reduce lane-partial l across hi, O /= l, packed short4 stores
  const int bb = bh >> 4, h = bh & 15;
#pragma unroll
  for (int f = 0; f < 2; ++f) {
    float l = l_i[f];
    l += __shfl_xor(l, 16);
    l += __shfl_xor(l, 32);
    float rl = 1.0f / l;
    int q = q0 + f * 16 + lrow;
#pragma unroll
    for (int db = 0; db < 4; ++db) {
      short4 pk;
      pk.x = bfc(accO[f][db][0] * rl);
      pk.y = bfc(accO[f][db][1] * rl);
      pk.z = bfc(accO[f][db][2] * rl);
      pk.w = bfc(accO[f][db][3] * rl);
      *(short4*)(Og + (size_t)(bb * LL + q) * DD + h * 64 + db * 16 + hi * 4) = pk;
    }
  }
}

// ---------------- output GEMM: attn[4096,1024] @ WOt + bO -> f32 ----------
__global__ __launch_bounds__(256) void out_gemm(const short* __restrict__ Ab,
                                                const short* __restrict__ Wt,
                                                const float* __restrict__ bO,
                                                float* __restrict__ Out) {
  __shared__ __align__(16) short As[128 * 32];
  __shared__ __align__(16) short Bs[128 * 32];

  const int tid = threadIdx.x;
  const int lane = tid & 63;
  const int wid = tid >> 6;
  const int m0 = blockIdx.y * 128;
  const int n0 = blockIdx.x * 128;

  const int wrow = wid >> 1, wcol = wid & 1;
  const int lrow = lane & 15;
  const int lk8 = (lane >> 4) * 8;
  const int srow = lane >> 2;
  const int scol = (lane & 3) * 8;

  f32x4 z4 = {0.f, 0.f, 0.f, 0.f};
  f32x4 acc[4][4];
#pragma unroll
  for (int i = 0; i < 4; ++i)
#pragma unroll
    for (int j = 0; j < 4; ++j) acc[i][j] = z4;

  for (int kt = 0; kt < DD; kt += 32) {
#pragma unroll
    for (int i = 0; i < 2; ++i) {
      int c = wid * 2 + i;
      gl_lds16(Ab + (size_t)(m0 + c * 16 + srow) * DD + kt + scol, As + c * 512);
      gl_lds16(Wt + (size_t)(n0 + c * 16 + srow) * DD + kt + scol, Bs + c * 512);
    }
    __syncthreads();
    b16x8 a[4], b[4];
#pragma unroll
    for (int i = 0; i < 4; ++i)
      a[i] = *(const b16x8*)(As + (wrow * 64 + i * 16 + lrow) * 32 + lk8);
#pragma unroll
    for (int j = 0; j < 4; ++j)
      b[j] = *(const b16x8*)(Bs + (wcol * 64 + j * 16 + lrow) * 32 + lk8);
#pragma unroll
    for (int i = 0; i < 4; ++i)
#pragma unroll
      for (int j = 0; j < 4; ++j)
        acc[i][j] = __builtin_amdgcn_mfma_f32_16x16x32_bf16(a[i], b[j], acc[i][j], 0, 0, 0);
    __syncthreads();
  }

  float bv[4];
#pragma unroll
  for (int j = 0; j < 4; ++j) bv[j] = bO[n0 + wcol * 64 + j * 16 + lrow];

  const int rbase = (lane >> 4) * 4;
#pragma unroll
  for (int i = 0; i < 4; ++i) {
    int gm = m0 + wrow * 64 + i * 16 + rbase;
#pragma unroll
    for (int j = 0; j < 4; ++j) {
      int gn = n0 + wcol * 64 + j * 16 + lrow;
#pragma unroll
      for (int r = 0; r < 4; ++r)
        Out[(size_t)(gm + r) * DD + gn] = acc[i][j][r] + bv[j];
    }
  }
}

extern "C" void kernel_launch(void* const* d_in, const int* in_sizes, int n_in,
                              void* d_out, int out_size, void* d_ws, size_t ws_size,
                              hipStream_t stream) {
  const float* X = (const float*)d_in[0];
  const float* WQ = (const float*)d_in[1];
  const float* bQ = (const float*)d_in[2];
  const float* WK = (const float*)d_in[3];
  const float* bK = (const float*)d_in[4];
  const float* WV = (const float*)d_in[5];
  const float* bV = (const float*)d_in[6];
  const float* WO = (const float*)d_in[7];
  const float* bO = (const float*)d_in[8];
  float* Out = (float*)d_out;

  // workspace layout (shorts): Xb 4M | Wt 4x1M | Q 4M | K 4M | Vt 4M | At 4M
  if (ws_size < (size_t)24 * 1024 * 1024 * 2) return;
  short* ws = (short*)d_ws;
  short* Xb = ws;
  short* Wt = Xb + (size_t)4096 * 1024;
  short* Qb = Wt + (size_t)4 * 1024 * 1024;
  short* Kb = Qb + (size_t)4096 * 1024;
  short* Vtb = Kb + (size_t)4096 * 1024;
  short* At = Vtb + (size_t)4096 * 1024;

  hipLaunchKernelGGL(xcvt, dim3(4096), dim3(256), 0, stream, X, Xb);
  hipLaunchKernelGGL(wtrans, dim3(32, 32, 4), dim3(256), 0, stream, WQ, WK, WV, WO, Wt);
  hipLaunchKernelGGL(qkv_gemm, dim3(24, 32), dim3(256), 0, stream, Xb, Wt, bQ, bK, bV,
                     Qb, Kb, Vtb);
  hipLaunchKernelGGL(attn, dim3(16, 32), dim3(256), 0, stream, Qb, Kb, Vtb, At);
  hipLaunchKernelGGL(out_gemm, dim3(8, 32), dim3(256), 0, stream, At,
                     Wt + (size_t)3 * 1024 * 1024, bO, Out);
}

// Round 10
// 115.651 us; speedup vs baseline: 1.6967x; 1.0195x over previous
//
#include <hip/hip_runtime.h>
#include <stdint.h>

#define BB 2
#define HH 16
#define LL 2048
#define DD 1024

typedef __bf16 b16x8 __attribute__((ext_vector_type(8)));
typedef __bf16 b16x4 __attribute__((ext_vector_type(4)));
typedef float f32x4 __attribute__((ext_vector_type(4)));

__device__ __forceinline__ short f2bf(float f) {
  unsigned u = __builtin_bit_cast(unsigned, f);
  return (short)((u + 0x7fffu + ((u >> 16) & 1u)) >> 16);
}

// native bf16 convert
__device__ __forceinline__ short bfc(float f) {
  return __builtin_bit_cast(short, static_cast<__bf16>(f));
}

__device__ __forceinline__ void gl_lds16(const void* gp, void* lp) {
  __builtin_amdgcn_global_load_lds(
      (const __attribute__((address_space(1))) void*)gp,
      (__attribute__((address_space(3))) void*)lp, 16, 0, 0);
}

// ---------------- X f32 -> bf16 ----------------
__global__ __launch_bounds__(256) void xcvt(const float* __restrict__ X,
                                            short* __restrict__ Xb) {
  int i = blockIdx.x * 256 + threadIdx.x;
  float4 v = ((const float4*)X)[i];
  short4 o;
  o.x = f2bf(v.x); o.y = f2bf(v.y); o.z = f2bf(v.z); o.w = f2bf(v.w);
  ((short4*)Xb)[i] = o;
}

// ---------------- W[k][n] f32 -> Wt[n][k] bf16 (4 mats via blockIdx.z) ------
__global__ __launch_bounds__(256) void wtrans(const float* __restrict__ W0,
                                              const float* __restrict__ W1,
                                              const float* __restrict__ W2,
                                              const float* __restrict__ W3,
                                              short* __restrict__ Wt) {
  __shared__ float t[32][33];
  const float* W = blockIdx.z == 0 ? W0 : blockIdx.z == 1 ? W1
                 : blockIdx.z == 2 ? W2 : W3;
  short* dst = Wt + (size_t)blockIdx.z * DD * DD;
  int tx = threadIdx.x & 31, ty0 = threadIdx.x >> 5;
  int nb = blockIdx.x * 32, kb = blockIdx.y * 32;
#pragma unroll
  for (int i = 0; i < 4; ++i)
    t[ty0 + i * 8][tx] = W[(size_t)(kb + ty0 + i * 8) * DD + nb + tx];
  __syncthreads();
#pragma unroll
  for (int i = 0; i < 4; ++i)
    dst[(size_t)(nb + ty0 + i * 8) * DD + kb + tx] = f2bf(t[tx][ty0 + i * 8]);
}

// ---------------- fused QKV GEMM: [4096,1024] @ Wt -> Q,K,Vt ---------------
__global__ __launch_bounds__(256) void qkv_gemm(const short* __restrict__ Xb,
                                                const short* __restrict__ Wall,
                                                const float* __restrict__ bQ,
                                                const float* __restrict__ bK,
                                                const float* __restrict__ bV,
                                                short* __restrict__ Qo,
                                                short* __restrict__ Ko,
                                                short* __restrict__ Vto) {
  __shared__ __align__(16) short As[128 * 32];
  __shared__ __align__(16) short Bs[128 * 32];

  const int tid = threadIdx.x;
  const int lane = tid & 63;
  const int wid = tid >> 6;
  const int m0 = blockIdx.y * 128;
  const int ng = blockIdx.x * 128;
  const int sel = ng >> 10;
  const int n0 = ng & 1023;
  const short* W = Wall + (size_t)sel * DD * DD;

  const int wrow = wid >> 1, wcol = wid & 1;
  const int lrow = lane & 15;
  const int lk8 = (lane >> 4) * 8;
  const int srow = lane >> 2;
  const int scol = (lane & 3) * 8;

  f32x4 z4 = {0.f, 0.f, 0.f, 0.f};
  f32x4 acc[4][4];
#pragma unroll
  for (int i = 0; i < 4; ++i)
#pragma unroll
    for (int j = 0; j < 4; ++j) acc[i][j] = z4;

  for (int kt = 0; kt < DD; kt += 32) {
#pragma unroll
    for (int i = 0; i < 2; ++i) {
      int c = wid * 2 + i;
      gl_lds16(Xb + (size_t)(m0 + c * 16 + srow) * DD + kt + scol, As + c * 512);
      gl_lds16(W + (size_t)(n0 + c * 16 + srow) * DD + kt + scol, Bs + c * 512);
    }
    __syncthreads();
    b16x8 a[4], b[4];
#pragma unroll
    for (int i = 0; i < 4; ++i)
      a[i] = *(const b16x8*)(As + (wrow * 64 + i * 16 + lrow) * 32 + lk8);
#pragma unroll
    for (int j = 0; j < 4; ++j)
      b[j] = *(const b16x8*)(Bs + (wcol * 64 + j * 16 + lrow) * 32 + lk8);
#pragma unroll
    for (int i = 0; i < 4; ++i)
#pragma unroll
      for (int j = 0; j < 4; ++j)
        acc[i][j] = __builtin_amdgcn_mfma_f32_16x16x32_bf16(a[i], b[j], acc[i][j], 0, 0, 0);
    __syncthreads();
  }

  const float* bias = sel == 0 ? bQ : sel == 1 ? bK : bV;
  float bv[4];
#pragma unroll
  for (int j = 0; j < 4; ++j) bv[j] = bias[n0 + wcol * 64 + j * 16 + lrow];

  const int rbase = (lane >> 4) * 4;
  if (sel == 2) {
    // V: write transposed (B,H,DK,L) with keys PERMUTED within each 64-tile:
    // addr(key)= (kf>>1)*32 + hi*8 + (kf&1)*4 + t  (kf=key>>4, hi=(key>>2)&3,
    // t=key&3), so the attention PV fragment = one contiguous 16B b128 read.
#pragma unroll
    for (int i = 0; i < 4; ++i) {
      int gm = m0 + wrow * 64 + i * 16 + rbase;
      int bb = gm >> 11, lb = gm & 2047;
      int x = lb & 63;
      int kf = x >> 4;
      int lbp = (lb & ~63) | ((kf >> 1) << 5) | (((x >> 2) & 3) << 3) | ((kf & 1) << 2);
#pragma unroll
      for (int j = 0; j < 4; ++j) {
        int gn = n0 + wcol * 64 + j * 16 + lrow;
        int h = gn >> 6, dk = gn & 63;
        short4 pk;
        pk.x = bfc(acc[i][j][0] + bv[j]);
        pk.y = bfc(acc[i][j][1] + bv[j]);
        pk.z = bfc(acc[i][j][2] + bv[j]);
        pk.w = bfc(acc[i][j][3] + bv[j]);
        *(short4*)(Vto + ((size_t)((bb * HH + h) * 64 + dk)) * LL + lbp) = pk;
      }
    }
  } else {
    short* dst = sel == 0 ? Qo : Ko;
    // Q: fold 1/sqrt(64) AND log2(e) so softmax runs in exp2 domain.
    float sc = sel == 0 ? 0.18033688011112042f : 1.0f;
#pragma unroll
    for (int i = 0; i < 4; ++i) {
      int gm = m0 + wrow * 64 + i * 16 + rbase;
#pragma unroll
      for (int j = 0; j < 4; ++j) {
        int gn = n0 + wcol * 64 + j * 16 + lrow;
        int h = gn >> 6, dk = gn & 63;
#pragma unroll
        for (int r = 0; r < 4; ++r) {
          int m = gm + r;
          int bb = m >> 11, lq = m & 2047;
          dst[((size_t)(bb * HH + h) * LL + lq) * 64 + dk] =
              bfc((acc[i][j][r] + bv[j]) * sc);
        }
      }
    }
  }
}

// ---------------- flash attention (swapped-operand, 3-ring pipeline) ------
// grid (16, 32): 128 q-rows/block, 4 waves x 32 rows, XCD-chunked swizzle.
// K/V LDS-staged in a 3-buffer ring with 2-tile-ahead gl_lds prefetch and
// COUNTED s_waitcnt vmcnt(4) + raw s_barrier (never drain to 0 in-loop):
// each wave issues exactly 4 gl_lds/tile, so vmcnt(4) retires tile t+1's
// loads while t+2's stay in flight across the barrier (T3+T4). V's key
// order is pre-permuted in memory -> PV fragment = conflict-free b128.
// S^T = mfma(K,Q) keeps P in-register; PV = mfma(V,P) -> O^T.
__global__ __launch_bounds__(256, 2) void attn(const short* __restrict__ Qg,
                                               const short* __restrict__ Kg,
                                               const short* __restrict__ Vt,
                                               short* __restrict__ Og) {
  __shared__ __align__(16) short Ks[3][64 * 64];  // [key][d], swizzled rows
  __shared__ __align__(16) short Vs[3][64 * 64];  // [d][perm-key], swizzled

  const int tid = threadIdx.x;
  const int lane = tid & 63;
  const int wid = tid >> 6;

  // bijective XCD-chunked swizzle: orig%8 = XCD -> 64 contiguous new ids
  // per XCD = 4 bh values -> KV set 2MB fits the 4MB per-XCD L2.
  const int orig = blockIdx.x + 16 * blockIdx.y;
  const int nid = (orig & 7) * 64 + (orig >> 3);
  const int bh = nid >> 4;
  const int q0 = (nid & 15) * 128 + wid * 32;

  const short* Qb = Qg + (size_t)bh * LL * 64;
  const short* Kb = Kg + (size_t)bh * LL * 64;
  const short* Vb = Vt + (size_t)bh * 64 * LL;

  const int lrow = lane & 15;
  const int hi = lane >> 4;     // 0..3
  const int hi8 = hi * 8;       // shorts
  const int hi16b = hi * 16;    // bytes
  const int r8 = lane >> 3;     // staging row within 8-row chunk
  const int c8 = lane & 7;
  const int swz8 = (c8 ^ r8) * 8;  // pre-swizzled global source offset (elems)

  // Q fragment: B-operand of swapped QK (col=q=lrow, k=hi*8+j)
  b16x8 qf[2][2];
#pragma unroll
  for (int f = 0; f < 2; ++f)
#pragma unroll
    for (int ks = 0; ks < 2; ++ks)
      qf[f][ks] = *(const b16x8*)(Qb + (size_t)(q0 + f * 16 + lrow) * 64 + ks * 32 + hi8);

  f32x4 z4 = {0.f, 0.f, 0.f, 0.f};
  f32x4 accO[2][4];            // accO[f][db]: O^T[d=db*16+hi*4+r][q=f*16+lrow]
  float m_i[2], l_i[2];        // per-q scalars; l_i LANE-PARTIAL across hi
#pragma unroll
  for (int f = 0; f < 2; ++f) {
#pragma unroll
    for (int d = 0; d < 4; ++d) accO[f][d] = z4;
    m_i[f] = -1e30f; l_i[f] = 0.f;
  }

  // stage tile kt_ into ring buffer buf_ (4 gl_lds per wave: 2 K + 2 V)
  auto stage = [&](int kt_, int buf_) {
#pragma unroll
    for (int i = 0; i < 2; ++i) {
      int c = wid * 2 + i;
      gl_lds16(Kb + (size_t)(kt_ * 64 + c * 8 + r8) * 64 + swz8, &Ks[buf_][c * 512]);
      gl_lds16(Vb + (size_t)(c * 8 + r8) * LL + kt_ * 64 + swz8, &Vs[buf_][c * 512]);
    }
  };

  // prologue: 2 tiles in flight
  stage(0, 0);
  stage(1, 1);
  asm volatile("s_waitcnt vmcnt(4)" ::: "memory");  // tile0 resident
  __builtin_amdgcn_s_barrier();

  int cur = 0;
  for (int kt = 0; kt < LL / 64; ++kt) {
    // prefetch tile kt+2 into ring slot cur+2 (stays in flight past barrier)
    if (kt + 2 < LL / 64) {
      int pb = cur + 2;
      if (pb >= 3) pb -= 3;
      stage(kt + 2, pb);
    }

    const short* ksb = &Ks[cur][0];
    const short* vsb = &Vs[cur][0];

    // S^T = mfma(K, Q): sacc[f][kf][r] = S[key=kf*16+hi*4+r][q=f*16+lrow]
    f32x4 sacc[2][4];
#pragma unroll
    for (int f = 0; f < 2; ++f)
#pragma unroll
      for (int kf = 0; kf < 4; ++kf) sacc[f][kf] = z4;

    __builtin_amdgcn_s_setprio(1);
#pragma unroll
    for (int kf = 0; kf < 4; ++kf) {
      int key = kf * 16 + lrow;
      int sw = (key & 7) << 4;
#pragma unroll
      for (int ks = 0; ks < 2; ++ks) {
        b16x8 kfr = *(const b16x8*)(ksb + key * 64 + (((ks * 64 + hi16b) ^ sw) >> 1));
#pragma unroll
        for (int f = 0; f < 2; ++f)
          sacc[f][kf] =
              __builtin_amdgcn_mfma_f32_16x16x32_bf16(kfr, qf[f][ks], sacc[f][kf], 0, 0, 0);
      }
    }
    __builtin_amdgcn_s_setprio(0);

    // ---- defer-max online softmax (keys lane-local) ----
    float lm[2];
#pragma unroll
    for (int f = 0; f < 2; ++f) {
      float mx = sacc[f][0][0];
#pragma unroll
      for (int kf = 0; kf < 4; ++kf)
#pragma unroll
        for (int r = 0; r < 4; ++r) mx = fmaxf(mx, sacc[f][kf][r]);
      lm[f] = mx;
    }
    float w = fmaxf(lm[0] - m_i[0], lm[1] - m_i[1]);

    if (!__all(w <= 8.0f)) {
      // rare path: reduce max across the 4 hi-lanes sharing each q, rescale
#pragma unroll
      for (int f = 0; f < 2; ++f) {
        float mx = lm[f];
        mx = fmaxf(mx, __shfl_xor(mx, 16));
        mx = fmaxf(mx, __shfl_xor(mx, 32));
        float mnew = fmaxf(m_i[f], mx);
        float corr = __builtin_amdgcn_exp2f(m_i[f] - mnew);
        l_i[f] *= corr;
        m_i[f] = mnew;
#pragma unroll
        for (int d = 0; d < 4; ++d) accO[f][d] *= corr;
      }
    }

    // P = exp2(S - m) packed straight into the PV B-fragment (own regs).
    // PV k-order: tau(ks, hi*8+j) = (2ks + (j>>2))*16 + hi*4 + (j&3)
    b16x8 pfr[2][2];
#pragma unroll
    for (int f = 0; f < 2; ++f) {
      float ps = 0.f;
#pragma unroll
      for (int kf = 0; kf < 4; ++kf)
#pragma unroll
        for (int r = 0; r < 4; ++r) {
          float p = __builtin_amdgcn_exp2f(sacc[f][kf][r] - m_i[f]);
          ps += p;
          pfr[f][kf >> 1][(kf & 1) * 4 + r] = static_cast<__bf16>(p);
        }
      l_i[f] += ps;
    }

    // V fragment (A-operand): permuted key layout -> one conflict-free b128
    b16x8 vfr[4][2];
#pragma unroll
    for (int db = 0; db < 4; ++db) {
      int row = db * 16 + lrow;
      int sw = (row & 7) << 4;
#pragma unroll
      for (int ks = 0; ks < 2; ++ks)
        vfr[db][ks] = *(const b16x8*)(vsb + row * 64 + (((ks * 64 + hi16b) ^ sw) >> 1));
    }

    // O^T += mfma(V, P)
    __builtin_amdgcn_s_setprio(1);
#pragma unroll
    for (int f = 0; f < 2; ++f)
#pragma unroll
      for (int db = 0; db < 4; ++db)
#pragma unroll
        for (int ks = 0; ks < 2; ++ks)
          accO[f][db] =
              __builtin_amdgcn_mfma_f32_16x16x32_bf16(vfr[db][ks], pfr[f][ks], accO[f][db], 0, 0, 0);
    __builtin_amdgcn_s_setprio(0);

    // retire tile kt+1's 4 loads; keep kt+2's in flight across the barrier
    if (kt + 2 < LL / 64) {
      asm volatile("s_waitcnt vmcnt(4)" ::: "memory");
      __builtin_amdgcn_s_barrier();
    } else if (kt + 1 < LL / 64) {
      asm volatile("s_waitcnt vmcnt(0)" ::: "memory");
      __builtin_amdgcn_s_barrier();
    }
    cur = cur + 1 >= 3 ? 0 : cur + 1;
  }

  // epilogue: reduce lane-partial l across hi, O /= l, packed short4 stores
  const int bb = bh >> 4, h = bh & 15;
#pragma unroll
  for (int f = 0; f < 2; ++f) {
    float l = l_i[f];
    l += __shfl_xor(l, 16);
    l += __shfl_xor(l, 32);
    float rl = 1.0f / l;
    int q = q0 + f * 16 + lrow;
#pragma unroll
    for (int db = 0; db < 4; ++db) {
      short4 pk;
      pk.x = bfc(accO[f][db][0] * rl);
      pk.y = bfc(accO[f][db][1] * rl);
      pk.z = bfc(accO[f][db][2] * rl);
      pk.w = bfc(accO[f][db][3] * rl);
      *(short4*)(Og + (size_t)(bb * LL + q) * DD + h * 64 + db * 16 + hi * 4) = pk;
    }
  }
}

// ---------------- output GEMM: attn[4096,1024] @ WOt + bO -> f32 ----------
__global__ __launch_bounds__(256) void out_gemm(const short* __restrict__ Ab,
                                                const short* __restrict__ Wt,
                                                const float* __restrict__ bO,
                                                float* __restrict__ Out) {
  __shared__ __align__(16) short As[128 * 32];
  __shared__ __align__(16) short Bs[128 * 32];

  const int tid = threadIdx.x;
  const int lane = tid & 63;
  const int wid = tid >> 6;
  const int m0 = blockIdx.y * 128;
  const int n0 = blockIdx.x * 128;

  const int wrow = wid >> 1, wcol = wid & 1;
  const int lrow = lane & 15;
  const int lk8 = (lane >> 4) * 8;
  const int srow = lane >> 2;
  const int scol = (lane & 3) * 8;

  f32x4 z4 = {0.f, 0.f, 0.f, 0.f};
  f32x4 acc[4][4];
#pragma unroll
  for (int i = 0; i < 4; ++i)
#pragma unroll
    for (int j = 0; j < 4; ++j) acc[i][j] = z4;

  for (int kt = 0; kt < DD; kt += 32) {
#pragma unroll
    for (int i = 0; i < 2; ++i) {
      int c = wid * 2 + i;
      gl_lds16(Ab + (size_t)(m0 + c * 16 + srow) * DD + kt + scol, As + c * 512);
      gl_lds16(Wt + (size_t)(n0 + c * 16 + srow) * DD + kt + scol, Bs + c * 512);
    }
    __syncthreads();
    b16x8 a[4], b[4];
#pragma unroll
    for (int i = 0; i < 4; ++i)
      a[i] = *(const b16x8*)(As + (wrow * 64 + i * 16 + lrow) * 32 + lk8);
#pragma unroll
    for (int j = 0; j < 4; ++j)
      b[j] = *(const b16x8*)(Bs + (wcol * 64 + j * 16 + lrow) * 32 + lk8);
#pragma unroll
    for (int i = 0; i < 4; ++i)
#pragma unroll
      for (int j = 0; j < 4; ++j)
        acc[i][j] = __builtin_amdgcn_mfma_f32_16x16x32_bf16(a[i], b[j], acc[i][j], 0, 0, 0);
    __syncthreads();
  }

  float bv[4];
#pragma unroll
  for (int j = 0; j < 4; ++j) bv[j] = bO[n0 + wcol * 64 + j * 16 + lrow];

  const int rbase = (lane >> 4) * 4;
#pragma unroll
  for (int i = 0; i < 4; ++i) {
    int gm = m0 + wrow * 64 + i * 16 + rbase;
#pragma unroll
    for (int j = 0; j < 4; ++j) {
      int gn = n0 + wcol * 64 + j * 16 + lrow;
#pragma unroll
      for (int r = 0; r < 4; ++r)
        Out[(size_t)(gm + r) * DD + gn] = acc[i][j][r] + bv[j];
    }
  }
}

extern "C" void kernel_launch(void* const* d_in, const int* in_sizes, int n_in,
                              void* d_out, int out_size, void* d_ws, size_t ws_size,
                              hipStream_t stream) {
  const float* X = (const float*)d_in[0];
  const float* WQ = (const float*)d_in[1];
  const float* bQ = (const float*)d_in[2];
  const float* WK = (const float*)d_in[3];
  const float* bK = (const float*)d_in[4];
  const float* WV = (const float*)d_in[5];
  const float* bV = (const float*)d_in[6];
  const float* WO = (const float*)d_in[7];
  const float* bO = (const float*)d_in[8];
  float* Out = (float*)d_out;

  // workspace layout (shorts): Xb 4M | Wt 4x1M | Q 4M | K 4M | Vt 4M | At 4M
  if (ws_size < (size_t)24 * 1024 * 1024 * 2) return;
  short* ws = (short*)d_ws;
  short* Xb = ws;
  short* Wt = Xb + (size_t)4096 * 1024;
  short* Qb = Wt + (size_t)4 * 1024 * 1024;
  short* Kb = Qb + (size_t)4096 * 1024;
  short* Vtb = Kb + (size_t)4096 * 1024;
  short* At = Vtb + (size_t)4096 * 1024;

  hipLaunchKernelGGL(xcvt, dim3(4096), dim3(256), 0, stream, X, Xb);
  hipLaunchKernelGGL(wtrans, dim3(32, 32, 4), dim3(256), 0, stream, WQ, WK, WV, WO, Wt);
  hipLaunchKernelGGL(qkv_gemm, dim3(24, 32), dim3(256), 0, stream, Xb, Wt, bQ, bK, bV,
                     Qb, Kb, Vtb);
  hipLaunchKernelGGL(attn, dim3(16, 32), dim3(256), 0, stream, Qb, Kb, Vtb, At);
  hipLaunchKernelGGL(out_gemm, dim3(8, 32), dim3(256), 0, stream, At,
                     Wt + (size_t)3 * 1024 * 1024, bO, Out);
}